// Round 9
// baseline (147.959 us; speedup 1.0000x reference)
//
#include <hip/hip_runtime.h>

namespace {

constexpr int kB  = 16;    // batches
constexpr int kP  = 8;     // pieces
constexpr int kNT = 512;   // time steps (incl. t=0)
constexpr int kNX = 2048;  // cells
constexpr int kLdsN = 1152;  // 64 lanes * 18 cells (max region)

// Cross-lane shift by one lane via DPP (VALU; no LDS round-trip).
__device__ __forceinline__ float dpp_shr1(float x) {
    return __builtin_bit_cast(float,
        __builtin_amdgcn_update_dpp(0, __builtin_bit_cast(int, x), 0x138, 0xF, 0xF, true));
}
__device__ __forceinline__ float dpp_shl1(float x) {
    return __builtin_bit_cast(float,
        __builtin_amdgcn_update_dpp(0, __builtin_bit_cast(int, x), 0x130, 0xF, 0xF, true));
}

__device__ __forceinline__ float fpar(float u) {  // f(u) = u - u^2
    return __builtin_fmaf(-u, u, u);
}

// Store the block's owned 128 cells (global cells [k*128, k*128+128)) of one row.
// Region layout: lane holds cells [rs + C*lane, rs + C*lane + C); owned cells sit
// at region offsets [32C-64, 32C+64).
// If C divides 64, ownership is lane-aligned -> direct float4 stores.
// Else stage the row through LDS (single wave: DS pipe is in-order per wave,
// so write->read needs no barrier) and emit one float2 per lane.
template<int C>
__device__ __forceinline__ void store_row(const float (&u)[18], int lane, int k,
                                          float* prow, float* lds, int par)
{
    if constexpr (64 % C == 0) {
        constexpr int l0 = (32 * C - 64) / C;
        constexpr int nl = 128 / C;
        if (lane >= l0 && lane < l0 + nl) {
            float* dst = prow + k * 128 + (lane - l0) * C;
#pragma unroll
            for (int j = 0; j < C; j += 4)
                *reinterpret_cast<float4*>(dst + j) =
                    make_float4(u[j], u[j + 1], u[j + 2], u[j + 3]);
        }
    } else {
        float* Lb = lds + par * kLdsN;  // double-buffer by step parity
        float* wp = Lb + C * lane;
#pragma unroll
        for (int j = 0; j < C; j += 2)
            *reinterpret_cast<float2*>(wp + j) = make_float2(u[j], u[j + 1]);
        float2 w = *reinterpret_cast<const float2*>(Lb + (32 * C - 64) + 2 * lane);
        *reinterpret_cast<float2*>(prow + k * 128 + 2 * lane) = w;
    }
}

// Re-pack register region C -> CN cells/lane (region start shifts +64 cells).
// New lane element (lane, j) = old region offset 64 + CN*lane + j. LDS is
// indexed by region offset; single-wave in-order DS makes write->read safe.
template<int C, int CN>
__device__ __forceinline__ void repack(float (&u)[18], int lane, float* lds)
{
    float* Rb = lds + 2 * kLdsN;
    float* wp = Rb + C * lane;
#pragma unroll
    for (int j = 0; j < C; j += 2)
        *reinterpret_cast<float2*>(wp + j) = make_float2(u[j], u[j + 1]);
    const float* rp = Rb + 64 + CN * lane;
#pragma unroll
    for (int j = 0; j < CN; j += 2) {
        float2 w = *reinterpret_cast<const float2*>(rp + j);
        u[j] = w.x; u[j + 1] = w.y;
    }
}

// One phase: nsteps Godunov steps at C cells/lane, storing each row.
// Ghost handling: a uniform-gL (gR) constant region is an exact fixed point of
// the flux, so only cell -1 (pin gL) and cell kNX (pin gR) need per-step
// pinning; done via 1 fma/cell blend, only in blocks whose region contains
// those cells (block-uniform branch).
template<int C>
__device__ __forceinline__ void run_phase(
    int nsteps, float (&u)[18], float lam, int lane, int k, int rs,
    float gL, float gR, float* prow, float* lds)
{
    const int  gi0     = rs + C * lane;
    const bool needPin = (rs < 0) || (rs + 64 * C > kNX);
    float pm_[18], pa_[18];
    if (needPin) {
#pragma unroll
        for (int j = 0; j < C; ++j) {
            int  gi   = gi0 + j;
            bool pinL = (gi == -1);
            bool pinR = (gi == kNX);
            pm_[j] = (pinL || pinR) ? 0.0f : 1.0f;
            pa_[j] = pinL ? gL : (pinR ? gR : 0.0f);
        }
    }

#pragma unroll 1
    for (int q = 0; q < nsteps; ++q) {
        float um = dpp_shr1(u[C - 1]);   // left neighbor of lane's first cell
        float up = dpp_shl1(u[0]);       // right neighbor of lane's last cell

        // Godunov flux, branchless concave form:
        //   F(uL,uR) = min( f(min(uL,1/2)), f(max(uR,1/2)) )
        float fl[18], fh[18];
#pragma unroll
        for (int c = 0; c < C; ++c) {
            fl[c] = fpar(fminf(u[c], 0.5f));
            fh[c] = fpar(fmaxf(u[c], 0.5f));
        }
        float flm = fpar(fminf(um, 0.5f));
        float fhp = fpar(fmaxf(up, 0.5f));

        float F[19];
        F[0] = fminf(flm, fh[0]);
#pragma unroll
        for (int c = 1; c < C; ++c) F[c] = fminf(fl[c - 1], fh[c]);
        F[C] = fminf(fl[C - 1], fhp);

#pragma unroll
        for (int c = 0; c < C; ++c)
            u[c] = __builtin_fmaf(-lam, F[c + 1] - F[c], u[c]);

        if (needPin) {
#pragma unroll
            for (int c = 0; c < C; ++c)
                u[c] = __builtin_fmaf(u[c], pm_[c], pa_[c]);  // exact: u*1+0 or gL/gR
        }

        store_row<C>(u, lane, k, prow, lds, q & 1);
        prow += kNX;
    }
}

__global__ __launch_bounds__(64)
void godunov_cone(const float* __restrict__ xs,   // (B, P+1)
                  const float* __restrict__ ks,   // (B, P)
                  const int*   __restrict__ pmask,// (B, P)
                  const float* __restrict__ dxp,  // (B,)
                  const float* __restrict__ dtp,  // (B,)
                  float* __restrict__ out)        // (B,1,NT,NX) fp32
{
    __shared__ float lds[3 * kLdsN];

    const int bx   = blockIdx.x;
    const int b    = bx >> 4;        // batch
    const int k    = bx & 15;        // chunk within batch
    const int lane = threadIdx.x;    // 0..63, one wave per block

    const float dxv = dxp[0];
    const float lam = dtp[0] / dxv;

    // ---- piecewise-constant IC parameters ----
    int np = 0;
    float bnds[kP];
#pragma unroll
    for (int j = 0; j < kP; ++j) {
        int m = pmask[b * kP + j];
        np += m;
        bnds[j] = m ? xs[b * (kP + 1) + j + 1] : __builtin_inff();
    }
    const int cap = np - 1;

    auto icval = [&](int gi) -> float {
        float xc = ((float)gi + 0.5f) * dxv;   // gi<0 -> gL, gi>=kNX -> gR
        int idx = 0;
#pragma unroll
        for (int j = 0; j < kP; ++j) idx += (xc >= bnds[j]) ? 1 : 0;
        return ks[b * kP + min(idx, cap)];
    };

    const float gL = icval(0);
    const float gR = icval(kNX - 1);

    // ---- seed full cone region at t=0: C=18, region [rs, rs+1152) ----
    int rs = k * 128 - (32 * 18 - 64);   // = k*128 - 512
    float u[18];
#pragma unroll
    for (int j = 0; j < 18; ++j) u[j] = icval(rs + 18 * lane + j);

    float* prow = out + (size_t)b * kNT * kNX;   // row 0
    store_row<18>(u, lane, k, prow, lds, 0);
    prow += kNX;

    // ---- 8 phases; cone shrinks 128 cells (2/lane) per 64 steps ----
    run_phase<18>(64, u, lam, lane, k, rs, gL, gR, prow, lds); prow += 64 * (size_t)kNX;
    repack<18, 16>(u, lane, lds); rs += 64;
    run_phase<16>(64, u, lam, lane, k, rs, gL, gR, prow, lds); prow += 64 * (size_t)kNX;
    repack<16, 14>(u, lane, lds); rs += 64;
    run_phase<14>(64, u, lam, lane, k, rs, gL, gR, prow, lds); prow += 64 * (size_t)kNX;
    repack<14, 12>(u, lane, lds); rs += 64;
    run_phase<12>(64, u, lam, lane, k, rs, gL, gR, prow, lds); prow += 64 * (size_t)kNX;
    repack<12, 10>(u, lane, lds); rs += 64;
    run_phase<10>(64, u, lam, lane, k, rs, gL, gR, prow, lds); prow += 64 * (size_t)kNX;
    repack<10, 8>(u, lane, lds); rs += 64;
    run_phase<8>(64, u, lam, lane, k, rs, gL, gR, prow, lds);  prow += 64 * (size_t)kNX;
    repack<8, 6>(u, lane, lds); rs += 64;
    run_phase<6>(64, u, lam, lane, k, rs, gL, gR, prow, lds);  prow += 64 * (size_t)kNX;
    repack<6, 4>(u, lane, lds); rs += 64;
    run_phase<4>(63, u, lam, lane, k, rs, gL, gR, prow, lds);  // rows 449..511
}

}  // namespace

extern "C" void kernel_launch(void* const* d_in, const int* in_sizes, int n_in,
                              void* d_out, int out_size, void* d_ws, size_t ws_size,
                              hipStream_t stream) {
    const float* xs  = (const float*)d_in[0];
    const float* ks  = (const float*)d_in[1];
    const int*   pmk = (const int*)d_in[2];
    const float* dxv = (const float*)d_in[3];
    const float* dtv = (const float*)d_in[4];
    // d_in[5] = t_coords: only carries the (NT, NX) shape; values unused.
    float* out = (float*)d_out;

    // Single launch, zero inter-block communication: each block computes its
    // chunk's full dependency cone from the IC (redundantly), shrinking the
    // register region 2 cells/lane every 64 steps.
    hipLaunchKernelGGL(godunov_cone, dim3(kB * 16), dim3(64), 0, stream,
                       xs, ks, pmk, dxv, dtv, out);
}

// Round 10
// 102.577 us; speedup vs baseline: 1.4424x; 1.4424x over previous
//
#include <hip/hip_runtime.h>

namespace {

constexpr int kB  = 16;    // batches
constexpr int kP  = 8;     // pieces
constexpr int kNT = 512;   // time steps (incl. t=0)
constexpr int kNX = 2048;  // cells
constexpr int kW  = 64;    // steps per super-step
constexpr int kChunk = 128;               // cells owned per wave
constexpr int kNS = 8;                    // super-steps: 7*64 + 63 = 511 rows
// region per wave = kChunk + 2*kW = 256 cells = 64 lanes x 4 cells

// d_ws layout. Flags are padded to one 128B cacheline EACH: packed flags put
// ~32 blocks' flags in one line, so every flag write invalidated the line all
// neighboring spinners were polling -> L2 re-fetch storm (R8: 659 MB FETCH,
// HBM-saturated). One line per flag kills the false sharing.
constexpr int    kFlagStride = 32;                                   // ints (128 B)
constexpr size_t kFlagsBytes = (size_t)kB * 16 * kNS * kFlagStride * 4;  // 256 KB
constexpr size_t kHaloOff    = 262144;                               // after flags

// Cross-lane shift by one lane via DPP (VALU; no LDS round-trip).
__device__ __forceinline__ float dpp_shr1(float x) {
    return __builtin_bit_cast(float,
        __builtin_amdgcn_update_dpp(0, __builtin_bit_cast(int, x), 0x138, 0xF, 0xF, true));
}
__device__ __forceinline__ float dpp_shl1(float x) {
    return __builtin_bit_cast(float,
        __builtin_amdgcn_update_dpp(0, __builtin_bit_cast(int, x), 0x130, 0xF, 0xF, true));
}

__device__ __forceinline__ float fpar(float u) {  // f(u) = u - u^2
    return __builtin_fmaf(-u, u, u);
}

// Relaxed agent-scope RMWs: execute at the coherence point, no acquire/release
// cache maintenance.
__device__ __forceinline__ void mall_store(int* p, float v) {
    (void)__hip_atomic_exchange(p, __builtin_bit_cast(int, v),
                                __ATOMIC_RELAXED, __HIP_MEMORY_SCOPE_AGENT);
}
__device__ __forceinline__ float mall_load(int* p) {
    return __builtin_bit_cast(float,
        __hip_atomic_fetch_add(p, 0, __ATOMIC_RELAXED, __HIP_MEMORY_SCOPE_AGENT));
}

__global__ __launch_bounds__(64)
void godunov_fused(const float* __restrict__ xs,   // (B, P+1)
                   const float* __restrict__ ks,   // (B, P)
                   const int*   __restrict__ pm,   // (B, P)
                   const float* __restrict__ dxp,  // (B,)
                   const float* __restrict__ dtp,  // (B,)
                   float* __restrict__ out,        // (B,1,NT,NX) fp32
                   int*   __restrict__ flags,      // [B*16*kNS] stride kFlagStride, pre-zeroed
                   int*   __restrict__ halo)       // [B][16][kNS][kChunk] (f32 bits)
{
    const int bx   = blockIdx.x;
    const int b    = bx >> 4;        // batch
    const int k    = bx & 15;        // chunk within batch
    const int lane = threadIdx.x;    // 0..63, one wave per block
    const int rs   = k * kChunk - kW;    // region start (may be <0)
    const int gi0  = rs + 4 * lane;      // this lane's first cell

    const float dxv = dxp[0];
    const float lam = dtp[0] / dxv;

    // ---- piecewise-constant IC parameters ----
    int np = 0;
    float bnds[kP];
#pragma unroll
    for (int j = 0; j < kP; ++j) {
        int m = pm[b * kP + j];
        np += m;
        bnds[j] = m ? xs[b * (kP + 1) + j + 1] : __builtin_inff();
    }
    const int cap = np - 1;

    auto icval = [&](int gi) -> float {
        float xc = ((float)gi + 0.5f) * dxv;
        int idx = 0;
#pragma unroll
        for (int j = 0; j < kP; ++j) idx += (xc >= bnds[j]) ? 1 : 0;
        idx = min(idx, cap);
        return ks[b * kP + idx];
    };

    // Constant ghost values (reference: frozen IC endpoints).
    const float gL = icval(0);
    const float gR = icval(kNX - 1);

    // Region is 4-aligned; each lane's 4 cells are all-in or all-out of domain.
    const bool  laneIn  = (gi0 >= 0) && (gi0 < kNX);
    const float gvv     = (gi0 < 0) ? gL : gR;
    const bool  edgeBlk = (k == 0) || (k == 15);   // only these ever pin

    // ---- seed at t=0 from IC ----
    float u[4];
#pragma unroll
    for (int c = 0; c < 4; ++c)
        u[c] = laneIn ? icval(gi0 + c) : gvv;

    // Lanes 16..47 own exactly the chunk (cells k*128 .. k*128+127).
    const bool writer = (lane >= 16) && (lane < 48);
    float* prow = out + ((size_t)b * kNT) * kNX;  // row 0

    if (writer)
        *reinterpret_cast<float4*>(prow + gi0) = make_float4(u[0], u[1], u[2], u[3]);

    const int fbase = (b * 16 + k) * kNS;

    auto do_step = [&]() {
        float um = dpp_shr1(u[3]);    // cell gi0-1
        float up = dpp_shl1(u[0]);    // cell gi0+4
        // Godunov flux, branchless concave form:
        //   F(uL,uR) = min( f(min(uL,1/2)), f(max(uR,1/2)) )
        float fl[4], fh[4];
#pragma unroll
        for (int c = 0; c < 4; ++c) {
            fl[c] = fpar(fminf(u[c], 0.5f));
            fh[c] = fpar(fmaxf(u[c], 0.5f));
        }
        float flm = fpar(fminf(um, 0.5f));
        float fhp = fpar(fmaxf(up, 0.5f));
        float F0 = fminf(flm,   fh[0]);
        float F1 = fminf(fl[0], fh[1]);
        float F2 = fminf(fl[1], fh[2]);
        float F3 = fminf(fl[2], fh[3]);
        float F4 = fminf(fl[3], fhp);
        u[0] = __builtin_fmaf(-lam, F1 - F0, u[0]);
        u[1] = __builtin_fmaf(-lam, F2 - F1, u[1]);
        u[2] = __builtin_fmaf(-lam, F3 - F2, u[2]);
        u[3] = __builtin_fmaf(-lam, F4 - F3, u[3]);
        if (edgeBlk) {   // wave-uniform; skipped by 14/16 blocks
#pragma unroll
            for (int c = 0; c < 4; ++c) u[c] = laneIn ? u[c] : gvv;
        }
    };

#pragma unroll 1
    for (int s = 0; s < kNS; ++s) {
        // ---- re-seed halo lanes from neighbors (state at time 64*s) ----
        if (s > 0) {
            const bool needL = (k > 0), needR = (k < 15);
            // lane-0-only slow poll: blocks do identical work, so skew is
            // sub-us; s_sleep(16) ~ 1k cyc between polls -> ~1-3 polls/sync.
            if (lane == 0) {
                int* fL = flags + ((b * 16 + (k - 1)) * kNS + s) * kFlagStride;
                int* fR = flags + ((b * 16 + (k + 1)) * kNS + s) * kFlagStride;
                int okL = needL ? 0 : 1, okR = needR ? 0 : 1;
                for (int it = 0; it < (1 << 20); ++it) {
                    if (!okL) okL = __hip_atomic_fetch_add(fL, 0, __ATOMIC_RELAXED,
                                                           __HIP_MEMORY_SCOPE_AGENT);
                    if (!okR) okR = __hip_atomic_fetch_add(fR, 0, __ATOMIC_RELAXED,
                                                           __HIP_MEMORY_SCOPE_AGENT);
                    if (okL && okR) break;
                    __builtin_amdgcn_s_sleep(16);
                }
            }
            asm volatile("" ::: "memory");   // keep data reads below the spin

            if (lane < 16) {
                if (needL) {  // left neighbor's cells 64..127
                    int* hp = halo + ((size_t)((b * 16 + (k - 1)) * kNS + s)) * kChunk
                            + 64 + 4 * lane;
#pragma unroll
                    for (int c = 0; c < 4; ++c) u[c] = mall_load(hp + c);
                }  // k==0: lanes stay pinned at gL
            } else if (lane >= 48) {
                if (needR) {  // right neighbor's cells 0..63
                    int* hp = halo + ((size_t)((b * 16 + (k + 1)) * kNS + s)) * kChunk
                            + 4 * (lane - 48);
#pragma unroll
                    for (int c = 0; c < 4; ++c) u[c] = mall_load(hp + c);
                }  // k==15: lanes stay pinned at gR
            }
            // lanes 16..47 keep their registers (own chunk, still valid)
        }

        const int nsteps = (s == kNS - 1) ? (kW - 1) : kW;  // 7*64 + 63 = 511

#pragma unroll 4
        for (int j = 0; j < nsteps; ++j) {
            do_step();
            prow += kNX;
            if (writer)
                *reinterpret_cast<float4*>(prow + gi0) = make_float4(u[0], u[1], u[2], u[3]);
        }

        // ---- publish own chunk state (time 64*(s+1)) + flag, all relaxed ----
        if (s < kNS - 1) {
            if (writer) {
                int* hp = halo + ((size_t)(fbase + (s + 1))) * kChunk + 4 * (lane - 16);
#pragma unroll
                for (int c = 0; c < 4; ++c) mall_store(hp + c, u[c]);
            }
            // drain data RMWs (vmcnt covers global atomics), then set flag at MALL
            asm volatile("s_waitcnt vmcnt(0)" ::: "memory");
            if (lane == 0)
                (void)__hip_atomic_exchange(flags + (fbase + (s + 1)) * kFlagStride, 1,
                                            __ATOMIC_RELAXED, __HIP_MEMORY_SCOPE_AGENT);
        }
    }
}

}  // namespace

extern "C" void kernel_launch(void* const* d_in, const int* in_sizes, int n_in,
                              void* d_out, int out_size, void* d_ws, size_t ws_size,
                              hipStream_t stream) {
    const float* xs  = (const float*)d_in[0];
    const float* ks  = (const float*)d_in[1];
    const int*   pm  = (const int*)d_in[2];
    const float* dxv = (const float*)d_in[3];
    const float* dtv = (const float*)d_in[4];
    // d_in[5] = t_coords: only carries the (NT, NX) shape; values unused.
    float* out = (float*)d_out;

    int* flags = (int*)d_ws;
    int* halo  = (int*)((char*)d_ws + kHaloOff);

    // Flags must be zeroed every call (d_ws is not re-poisoned between replays).
    hipMemsetAsync(flags, 0, kFlagsBytes, stream);

    hipLaunchKernelGGL(godunov_fused, dim3(kB * 16), dim3(64), 0, stream,
                       xs, ks, pm, dxv, dtv, out, flags, halo);
}

// Round 11
// 93.165 us; speedup vs baseline: 1.5881x; 1.1010x over previous
//
#include <hip/hip_runtime.h>

namespace {

constexpr int kB  = 16;    // batches
constexpr int kP  = 8;     // pieces
constexpr int kNT = 512;   // time steps (incl. t=0)
constexpr int kNX = 2048;  // cells
constexpr int kW  = 64;    // steps per super-step
constexpr int kChunk = 128;               // cells owned per wave
constexpr int kNS = 8;                    // super-steps: 7*64 + 63 = 511 rows
// region per wave = kChunk + 2*kW = 256 cells = 64 lanes x 4 cells

// d_ws layout (R8 scheme: packed flags were fine — FETCH_SIZE is KB, the
// "fetch storm" was a units misread; R8 sync is near-free, blocks lockstep)
constexpr size_t kFlagsBytes = (size_t)kB * 16 * kNS * 4;   // 8 KB
constexpr size_t kHaloOff    = 32768;                       // int halo[B][16][kNS][kChunk]

// Cross-lane shift by one lane via DPP (VALU; no LDS round-trip).
__device__ __forceinline__ float dpp_shr1(float x) {
    return __builtin_bit_cast(float,
        __builtin_amdgcn_update_dpp(0, __builtin_bit_cast(int, x), 0x138, 0xF, 0xF, true));
}
__device__ __forceinline__ float dpp_shl1(float x) {
    return __builtin_bit_cast(float,
        __builtin_amdgcn_update_dpp(0, __builtin_bit_cast(int, x), 0x130, 0xF, 0xF, true));
}

__device__ __forceinline__ float fpar(float u) {  // f(u) = u - u^2
    return __builtin_fmaf(-u, u, u);
}

// Relaxed agent-scope RMWs (coherence-point ops, no cache maintenance).
__device__ __forceinline__ void mall_store(int* p, float v) {
    (void)__hip_atomic_exchange(p, __builtin_bit_cast(int, v),
                                __ATOMIC_RELAXED, __HIP_MEMORY_SCOPE_AGENT);
}
__device__ __forceinline__ float mall_load(int* p) {
    return __builtin_bit_cast(float,
        __hip_atomic_fetch_add(p, 0, __ATOMIC_RELAXED, __HIP_MEMORY_SCOPE_AGENT));
}

__global__ __launch_bounds__(64)
void godunov_fused(const float* __restrict__ xs,   // (B, P+1)
                   const float* __restrict__ ks,   // (B, P)
                   const int*   __restrict__ pm,   // (B, P)
                   const float* __restrict__ dxp,  // (B,)
                   const float* __restrict__ dtp,  // (B,)
                   float* __restrict__ out,        // (B,1,NT,NX) fp32
                   int*   __restrict__ flags,      // [B][16][kNS], pre-zeroed
                   int*   __restrict__ halo)       // [B][16][kNS][kChunk] (f32 bits)
{
    // Row staging buffer: per-step stores go here (DS ack ~64cyc < step time,
    // so the compiler's WAR lgkmcnt waits are always already satisfied); global
    // gets one bulk 16-row coalesced flush whose registers aren't reused for
    // ~16 steps -> the ~350cyc global-store ack never blocks anything.
    __shared__ float rowbuf[16][kChunk];   // 8 KB

    const int bx   = blockIdx.x;
    const int b    = bx >> 4;        // batch
    const int k    = bx & 15;        // chunk within batch
    const int lane = threadIdx.x;    // 0..63, one wave per block
    const int rs   = k * kChunk - kW;    // region start (may be <0)
    const int gi0  = rs + 4 * lane;      // this lane's first cell

    const float dxv = dxp[0];
    const float lam = dtp[0] / dxv;

    // ---- piecewise-constant IC parameters ----
    int np = 0;
    float bnds[kP];
#pragma unroll
    for (int j = 0; j < kP; ++j) {
        int m = pm[b * kP + j];
        np += m;
        bnds[j] = m ? xs[b * (kP + 1) + j + 1] : __builtin_inff();
    }
    const int cap = np - 1;

    auto icval = [&](int gi) -> float {
        float xc = ((float)gi + 0.5f) * dxv;
        int idx = 0;
#pragma unroll
        for (int j = 0; j < kP; ++j) idx += (xc >= bnds[j]) ? 1 : 0;
        idx = min(idx, cap);
        return ks[b * kP + idx];
    };

    // Constant ghost values (reference: frozen IC endpoints).
    const float gL = icval(0);
    const float gR = icval(kNX - 1);

    // Region is 4-aligned; each lane's 4 cells are all-in or all-out of domain.
    const bool  laneIn  = (gi0 >= 0) && (gi0 < kNX);
    const float gvv     = (gi0 < 0) ? gL : gR;
    const bool  edgeBlk = (k == 0) || (k == 15);   // only these ever pin

    // ---- seed at t=0 from IC ----
    float u[4];
#pragma unroll
    for (int c = 0; c < 4; ++c)
        u[c] = laneIn ? icval(gi0 + c) : gvv;

    // Lanes 16..47 own exactly the chunk (cells k*128 .. k*128+127).
    const bool writer = (lane >= 16) && (lane < 48);

    if (writer) {   // row 0 = IC, direct store (off the hot loop)
        float* p0 = out + ((size_t)b * kNT) * kNX;
        *reinterpret_cast<float4*>(p0 + gi0) = make_float4(u[0], u[1], u[2], u[3]);
    }

    const int col   = (lane & 31) * 4;   // flush column (floats within chunk)
    const int half  = lane >> 5;         // flush row parity
    const int fbase = (b * 16 + k) * kNS;
    int trow = 1;                        // next output row index

    auto do_step = [&]() {
        float um = dpp_shr1(u[3]);    // cell gi0-1
        float up = dpp_shl1(u[0]);    // cell gi0+4
        // Godunov flux, branchless concave form:
        //   F(uL,uR) = min( f(min(uL,1/2)), f(max(uR,1/2)) )
        float fl[4], fh[4];
#pragma unroll
        for (int c = 0; c < 4; ++c) {
            fl[c] = fpar(fminf(u[c], 0.5f));
            fh[c] = fpar(fmaxf(u[c], 0.5f));
        }
        float flm = fpar(fminf(um, 0.5f));
        float fhp = fpar(fmaxf(up, 0.5f));
        float F0 = fminf(flm,   fh[0]);
        float F1 = fminf(fl[0], fh[1]);
        float F2 = fminf(fl[1], fh[2]);
        float F3 = fminf(fl[2], fh[3]);
        float F4 = fminf(fl[3], fhp);
        u[0] = __builtin_fmaf(-lam, F1 - F0, u[0]);
        u[1] = __builtin_fmaf(-lam, F2 - F1, u[1]);
        u[2] = __builtin_fmaf(-lam, F3 - F2, u[2]);
        u[3] = __builtin_fmaf(-lam, F4 - F3, u[3]);
        if (edgeBlk) {   // wave-uniform; skipped by 14/16 blocks
#pragma unroll
            for (int c = 0; c < 4; ++c) u[c] = laneIn ? u[c] : gvv;
        }
    };

    auto stage = [&](int q) {   // LDS-stage own cells of the current row
        if (writer)
            *reinterpret_cast<float4*>(&rowbuf[q][(lane - 16) * 4]) =
                make_float4(u[0], u[1], u[2], u[3]);
    };

    auto flush = [&](int nrows) {  // bulk-store nrows staged rows, coalesced
        float* gb = out + ((size_t)b * kNT + trow) * kNX + k * kChunk + col;
        for (int r = half; r < nrows; r += 2) {   // 64 lanes cover 2 rows/iter
            float4 v = *reinterpret_cast<const float4*>(&rowbuf[r][col]);
            *reinterpret_cast<float4*>(gb + (size_t)r * kNX) = v;
        }
        trow += nrows;
    };

#pragma unroll 1
    for (int s = 0; s < kNS; ++s) {
        // ---- re-seed halo lanes from neighbors (state at time 64*s) ----
        if (s > 0) {
            const bool needL = (k > 0), needR = (k < 15);
            if (lane == 0) {   // lane-0-only poll, whole wave waits on branch
                int* fL = flags + ((b * 16 + (k - 1)) * kNS + s);
                int* fR = flags + ((b * 16 + (k + 1)) * kNS + s);
                int okL = needL ? 0 : 1, okR = needR ? 0 : 1;
                for (int it = 0; it < (1 << 22); ++it) {
                    if (!okL) okL = __hip_atomic_fetch_add(fL, 0, __ATOMIC_RELAXED,
                                                           __HIP_MEMORY_SCOPE_AGENT);
                    if (!okR) okR = __hip_atomic_fetch_add(fR, 0, __ATOMIC_RELAXED,
                                                           __HIP_MEMORY_SCOPE_AGENT);
                    if (okL && okR) break;
                    __builtin_amdgcn_s_sleep(4);
                }
            }
            asm volatile("" ::: "memory");   // keep data reads below the spin

            if (lane < 16) {
                if (needL) {  // left neighbor's cells 64..127
                    int* hp = halo + ((size_t)((b * 16 + (k - 1)) * kNS + s)) * kChunk
                            + 64 + 4 * lane;
#pragma unroll
                    for (int c = 0; c < 4; ++c) u[c] = mall_load(hp + c);
                }  // k==0: lanes stay pinned at gL
            } else if (lane >= 48) {
                if (needR) {  // right neighbor's cells 0..63
                    int* hp = halo + ((size_t)((b * 16 + (k + 1)) * kNS + s)) * kChunk
                            + 4 * (lane - 48);
#pragma unroll
                    for (int c = 0; c < 4; ++c) u[c] = mall_load(hp + c);
                }  // k==15: lanes stay pinned at gR
            }
            // lanes 16..47 keep their registers (own chunk, still valid)
        }

        // ---- 64 steps (last super-step: 63), staged via LDS, flushed by 16 ----
        const int ngroups = (s == kNS - 1) ? 3 : 4;
#pragma unroll 1
        for (int g = 0; g < ngroups; ++g) {
#pragma unroll
            for (int q = 0; q < 16; ++q) { do_step(); stage(q); }
            flush(16);
        }
        if (s == kNS - 1) {   // tail 15 steps -> rows 497..511
#pragma unroll
            for (int q = 0; q < 15; ++q) { do_step(); stage(q); }
            flush(15);
        }

        // ---- publish own chunk state (time 64*(s+1)) + flag, all relaxed ----
        if (s < kNS - 1) {
            if (writer) {
                int* hp = halo + ((size_t)(fbase + (s + 1))) * kChunk + 4 * (lane - 16);
#pragma unroll
                for (int c = 0; c < 4; ++c) mall_store(hp + c, u[c]);
            }
            // drain data RMWs (vmcnt covers global atomics), then set flag
            asm volatile("s_waitcnt vmcnt(0)" ::: "memory");
            if (lane == 0)
                (void)__hip_atomic_exchange(flags + fbase + (s + 1), 1,
                                            __ATOMIC_RELAXED, __HIP_MEMORY_SCOPE_AGENT);
        }
    }
}

}  // namespace

extern "C" void kernel_launch(void* const* d_in, const int* in_sizes, int n_in,
                              void* d_out, int out_size, void* d_ws, size_t ws_size,
                              hipStream_t stream) {
    const float* xs  = (const float*)d_in[0];
    const float* ks  = (const float*)d_in[1];
    const int*   pm  = (const int*)d_in[2];
    const float* dxv = (const float*)d_in[3];
    const float* dtv = (const float*)d_in[4];
    // d_in[5] = t_coords: only carries the (NT, NX) shape; values unused.
    float* out = (float*)d_out;

    int* flags = (int*)d_ws;
    int* halo  = (int*)((char*)d_ws + kHaloOff);

    // Flags must be zeroed every call (d_ws is not re-poisoned between replays).
    hipMemsetAsync(flags, 0, kFlagsBytes, stream);

    hipLaunchKernelGGL(godunov_fused, dim3(kB * 16), dim3(64), 0, stream,
                       xs, ks, pm, dxv, dtv, out, flags, halo);
}

// Round 12
// 92.617 us; speedup vs baseline: 1.5975x; 1.0059x over previous
//
#include <hip/hip_runtime.h>

namespace {

constexpr int kB  = 16;    // batches
constexpr int kP  = 8;     // pieces
constexpr int kNT = 512;   // time steps (incl. t=0)
constexpr int kNX = 2048;  // cells
constexpr int kW  = 64;    // steps per super-step
constexpr int kChunk = 128;               // cells owned per wave
constexpr int kNS = 8;                    // super-steps: 7*64 + 63 = 511 rows
// region per wave = kChunk + 2*kW = 256 cells = 64 lanes x 4 cells

// d_ws layout
constexpr size_t kFlagsBytes = (size_t)kB * 16 * kNS * 4;   // 8 KB
constexpr size_t kHaloOff    = 32768;                       // int halo[B][16][kNS][kChunk]

// Cross-lane shift by one lane via DPP (VALU; no LDS round-trip).
__device__ __forceinline__ float dpp_shr1(float x) {
    return __builtin_bit_cast(float,
        __builtin_amdgcn_update_dpp(0, __builtin_bit_cast(int, x), 0x138, 0xF, 0xF, true));
}
__device__ __forceinline__ float dpp_shl1(float x) {
    return __builtin_bit_cast(float,
        __builtin_amdgcn_update_dpp(0, __builtin_bit_cast(int, x), 0x130, 0xF, 0xF, true));
}

__device__ __forceinline__ float fpar(float u) {  // f(u) = u - u^2
    return __builtin_fmaf(-u, u, u);
}

// Relaxed agent-scope RMWs (coherence-point ops, no cache maintenance).
__device__ __forceinline__ void mall_store(int* p, float v) {
    (void)__hip_atomic_exchange(p, __builtin_bit_cast(int, v),
                                __ATOMIC_RELAXED, __HIP_MEMORY_SCOPE_AGENT);
}
__device__ __forceinline__ float mall_load(int* p) {
    return __builtin_bit_cast(float,
        __hip_atomic_fetch_add(p, 0, __ATOMIC_RELAXED, __HIP_MEMORY_SCOPE_AGENT));
}

__global__ __launch_bounds__(64)
void godunov_fused(const float* __restrict__ xs,   // (B, P+1)
                   const float* __restrict__ ks,   // (B, P)
                   const int*   __restrict__ pm,   // (B, P)
                   const float* __restrict__ dxp,  // (B,)
                   const float* __restrict__ dtp,  // (B,)
                   float* __restrict__ out,        // (B,1,NT,NX) fp32
                   int*   __restrict__ flags,      // [B][16][kNS], pre-zeroed
                   int*   __restrict__ halo)       // [B][16][kNS][kChunk] (f32 bits)
{
    // Per-step stores go to LDS (ds_write ack ~64cyc < step time, so WAR
    // lgkm waits are pre-satisfied). Global flush is FULLY UNROLLED so the
    // compiler renames 8 data + 8 address registers: all acks overlap the
    // next 16 compute steps. (Rolled flush = 1 reg recycled = ds_read 120cyc
    // + store-ack ~350cyc serialized per iteration = the hidden 50 us that
    // kept R8..R11 at ~86 us.)
    __shared__ float rowbuf[16][kChunk];   // 8 KB

    const int bx   = blockIdx.x;
    const int b    = bx >> 4;        // batch
    const int k    = bx & 15;        // chunk within batch
    const int lane = threadIdx.x;    // 0..63, one wave per block
    const int rs   = k * kChunk - kW;    // region start (may be <0)
    const int gi0  = rs + 4 * lane;      // this lane's first cell

    const float dxv = dxp[0];
    const float lam = dtp[0] / dxv;

    // ---- piecewise-constant IC parameters ----
    int np = 0;
    float bnds[kP];
#pragma unroll
    for (int j = 0; j < kP; ++j) {
        int m = pm[b * kP + j];
        np += m;
        bnds[j] = m ? xs[b * (kP + 1) + j + 1] : __builtin_inff();
    }
    const int cap = np - 1;

    auto icval = [&](int gi) -> float {
        float xc = ((float)gi + 0.5f) * dxv;
        int idx = 0;
#pragma unroll
        for (int j = 0; j < kP; ++j) idx += (xc >= bnds[j]) ? 1 : 0;
        idx = min(idx, cap);
        return ks[b * kP + idx];
    };

    // Constant ghost values (reference: frozen IC endpoints).
    const float gL = icval(0);
    const float gR = icval(kNX - 1);

    // Region is 4-aligned; each lane's 4 cells are all-in or all-out of domain.
    const bool  laneIn  = (gi0 >= 0) && (gi0 < kNX);
    const float gvv     = (gi0 < 0) ? gL : gR;
    const bool  edgeBlk = (k == 0) || (k == 15);   // only these ever pin

    // ---- seed at t=0 from IC ----
    float u[4];
#pragma unroll
    for (int c = 0; c < 4; ++c)
        u[c] = laneIn ? icval(gi0 + c) : gvv;

    // Lanes 16..47 own exactly the chunk (cells k*128 .. k*128+127).
    const bool writer = (lane >= 16) && (lane < 48);

    if (writer) {   // row 0 = IC, direct store (off the hot loop)
        float* p0 = out + ((size_t)b * kNT) * kNX;
        *reinterpret_cast<float4*>(p0 + gi0) = make_float4(u[0], u[1], u[2], u[3]);
    }

    const int col   = (lane & 31) * 4;   // flush column (floats within chunk)
    const int half  = lane >> 5;         // flush row parity
    const int fbase = (b * 16 + k) * kNS;
    int trow = 1;                        // next output row index

    auto do_step = [&]() {
        float um = dpp_shr1(u[3]);    // cell gi0-1
        float up = dpp_shl1(u[0]);    // cell gi0+4
        // Godunov flux, branchless concave form:
        //   F(uL,uR) = min( f(min(uL,1/2)), f(max(uR,1/2)) )
        float fl[4], fh[4];
#pragma unroll
        for (int c = 0; c < 4; ++c) {
            fl[c] = fpar(fminf(u[c], 0.5f));
            fh[c] = fpar(fmaxf(u[c], 0.5f));
        }
        float flm = fpar(fminf(um, 0.5f));
        float fhp = fpar(fmaxf(up, 0.5f));
        float F0 = fminf(flm,   fh[0]);
        float F1 = fminf(fl[0], fh[1]);
        float F2 = fminf(fl[1], fh[2]);
        float F3 = fminf(fl[2], fh[3]);
        float F4 = fminf(fl[3], fhp);
        u[0] = __builtin_fmaf(-lam, F1 - F0, u[0]);
        u[1] = __builtin_fmaf(-lam, F2 - F1, u[1]);
        u[2] = __builtin_fmaf(-lam, F3 - F2, u[2]);
        u[3] = __builtin_fmaf(-lam, F4 - F3, u[3]);
        if (edgeBlk) {   // wave-uniform; skipped by 14/16 blocks
#pragma unroll
            for (int c = 0; c < 4; ++c) u[c] = laneIn ? u[c] : gvv;
        }
    };

    auto stage = [&](int q) {   // LDS-stage own cells of the current row
        if (writer)
            *reinterpret_cast<float4*>(&rowbuf[q][(lane - 16) * 4]) =
                make_float4(u[0], u[1], u[2], u[3]);
    };

    // Bulk-store NR staged rows. Compile-time trip count + predication ->
    // full unroll, renamed regs, overlapped acks.
    auto flush = [&](int nrows) {
        float* gb = out + ((size_t)b * kNT + trow) * kNX + k * kChunk + col;
#pragma unroll
        for (int i = 0; i < 8; ++i) {
            int r = 2 * i + half;
            if (r < nrows) {
                float4 v = *reinterpret_cast<const float4*>(&rowbuf[r][col]);
                *reinterpret_cast<float4*>(gb + (size_t)r * kNX) = v;
            }
        }
        trow += nrows;
    };

#pragma unroll 1
    for (int s = 0; s < kNS; ++s) {
        // ---- re-seed halo lanes from neighbors (state at time 64*s) ----
        if (s > 0) {
            const bool needL = (k > 0), needR = (k < 15);
            if (lane == 0) {   // lane-0-only poll, whole wave waits on branch
                int* fL = flags + ((b * 16 + (k - 1)) * kNS + s);
                int* fR = flags + ((b * 16 + (k + 1)) * kNS + s);
                int okL = needL ? 0 : 1, okR = needR ? 0 : 1;
                for (int it = 0; it < (1 << 22); ++it) {
                    if (!okL) okL = __hip_atomic_fetch_add(fL, 0, __ATOMIC_RELAXED,
                                                           __HIP_MEMORY_SCOPE_AGENT);
                    if (!okR) okR = __hip_atomic_fetch_add(fR, 0, __ATOMIC_RELAXED,
                                                           __HIP_MEMORY_SCOPE_AGENT);
                    if (okL && okR) break;
                    __builtin_amdgcn_s_sleep(4);
                }
            }
            asm volatile("" ::: "memory");   // keep data reads below the spin

            if (lane < 16) {
                if (needL) {  // left neighbor's cells 64..127
                    int* hp = halo + ((size_t)((b * 16 + (k - 1)) * kNS + s)) * kChunk
                            + 64 + 4 * lane;
#pragma unroll
                    for (int c = 0; c < 4; ++c) u[c] = mall_load(hp + c);
                }  // k==0: lanes stay pinned at gL
            } else if (lane >= 48) {
                if (needR) {  // right neighbor's cells 0..63
                    int* hp = halo + ((size_t)((b * 16 + (k + 1)) * kNS + s)) * kChunk
                            + 4 * (lane - 48);
#pragma unroll
                    for (int c = 0; c < 4; ++c) u[c] = mall_load(hp + c);
                }  // k==15: lanes stay pinned at gR
            }
            // lanes 16..47 keep their registers (own chunk, still valid)
        }

        // ---- 64 steps (last super-step: 63), staged via LDS, flushed by 16 ----
        const int ngroups = (s == kNS - 1) ? 3 : 4;
#pragma unroll 1
        for (int g = 0; g < ngroups; ++g) {
#pragma unroll
            for (int q = 0; q < 16; ++q) { do_step(); stage(q); }
            flush(16);
        }
        if (s == kNS - 1) {   // tail 15 steps -> rows 497..511
#pragma unroll
            for (int q = 0; q < 15; ++q) { do_step(); stage(q); }
            flush(15);
        }

        // ---- publish own chunk state (time 64*(s+1)) + flag, all relaxed ----
        if (s < kNS - 1) {
            if (writer) {
                int* hp = halo + ((size_t)(fbase + (s + 1))) * kChunk + 4 * (lane - 16);
#pragma unroll
                for (int c = 0; c < 4; ++c) mall_store(hp + c, u[c]);
            }
            // drain data RMWs (vmcnt covers global atomics), then set flag
            asm volatile("s_waitcnt vmcnt(0)" ::: "memory");
            if (lane == 0)
                (void)__hip_atomic_exchange(flags + fbase + (s + 1), 1,
                                            __ATOMIC_RELAXED, __HIP_MEMORY_SCOPE_AGENT);
        }
    }
}

}  // namespace

extern "C" void kernel_launch(void* const* d_in, const int* in_sizes, int n_in,
                              void* d_out, int out_size, void* d_ws, size_t ws_size,
                              hipStream_t stream) {
    const float* xs  = (const float*)d_in[0];
    const float* ks  = (const float*)d_in[1];
    const int*   pm  = (const int*)d_in[2];
    const float* dxv = (const float*)d_in[3];
    const float* dtv = (const float*)d_in[4];
    // d_in[5] = t_coords: only carries the (NT, NX) shape; values unused.
    float* out = (float*)d_out;

    int* flags = (int*)d_ws;
    int* halo  = (int*)((char*)d_ws + kHaloOff);

    // Flags must be zeroed every call (d_ws is not re-poisoned between replays).
    hipMemsetAsync(flags, 0, kFlagsBytes, stream);

    hipLaunchKernelGGL(godunov_fused, dim3(kB * 16), dim3(64), 0, stream,
                       xs, ks, pm, dxv, dtv, out, flags, halo);
}